// Round 5
// baseline (2528.286 us; speedup 1.0000x reference)
//
#include <hip/hip_runtime.h>
#include <cmath>

namespace {
constexpr int kNH = 8;
constexpr int kNG = 1024;   // 32*32 groups
constexpr float kScale = 0.17677669529663687f;  // 32^-0.5
}

typedef short  bf16x8 __attribute__((ext_vector_type(8)));
typedef short  bf16x4 __attribute__((ext_vector_type(4)));
typedef float  f32x4  __attribute__((ext_vector_type(4)));

__device__ __forceinline__ unsigned short f2b(float f) {
  unsigned int u = __builtin_bit_cast(unsigned int, f);
  u += 0x7fffu + ((u >> 16) & 1u);          // RNE
  return (unsigned short)(u >> 16);
}
__device__ __forceinline__ float b2f(unsigned short h) {
  unsigned int u = ((unsigned int)h) << 16;
  return __builtin_bit_cast(float, u);
}
// vt column swizzle (k_attn): spreads d-major scalar writes across banks.
__device__ __forceinline__ int swc(int row, int col) {
  return col ^ (((row >> 3) & 3) << 3);
}

// ---------------- k_wcvt: w_qkv (768x256) -> bf16; w_out (256x256) -> bf16 hi+lo ----
__global__ void __launch_bounds__(256) k_wcvt(const float* __restrict__ w_qkv,
                                              const float* __restrict__ w_out,
                                              unsigned short* __restrict__ wb,
                                              unsigned short* __restrict__ w_hi,
                                              unsigned short* __restrict__ w_lo) {
  int i = blockIdx.x * 256 + threadIdx.x;   // grid 1024 -> 262144
  if (i < 196608) {
    wb[i] = f2b(w_qkv[i]);
  } else {
    int k = i - 196608;                     // < 65536
    float v = w_out[k];
    unsigned short h = f2b(v);
    w_hi[k] = h;
    w_lo[k] = f2b(v - b2f(h));              // hi+lo ~ fp32-accurate weight
  }
}

// ---------------- k_wqkcvt: w_qk (512x256) -> bf16 hi+lo ------------------------
__global__ void __launch_bounds__(256) k_wqkcvt(const float* __restrict__ w_qk,
                                                unsigned short* __restrict__ hi,
                                                unsigned short* __restrict__ lo) {
  int i = blockIdx.x * 256 + threadIdx.x;   // grid 512 -> 131072
  float v = w_qk[i];
  unsigned short h = f2b(v);
  hi[i] = h;
  lo[i] = f2b(v - b2f(h));
}

// ---------------- k_tok: qkv of the group token (shared by ALL windows) ---------
__global__ void __launch_bounds__(256) k_tok(const float* __restrict__ w_qkv,
                                             const float* __restrict__ gtok,
                                             unsigned short* __restrict__ tok_b) {
  int o = blockIdx.x * 256 + threadIdx.x;   // grid 3 -> 768
  if (o < 768) {
    float s = 0.f;
    for (int c = 0; c < 256; ++c) s += w_qkv[o * 256 + c] * gtok[c];
    tok_b[o] = f2b(s);
  }
}

// ---------------- k_xt: x[b][c][9216] fp32 -> xt[(b-b0)*9216+p][256] bf16 --------
__global__ void __launch_bounds__(256, 2)
k_xt(const float* __restrict__ x, unsigned short* __restrict__ xt, int b0) {
  __shared__ short Lt[64][72];
  const int tid = threadIdx.x;
  const int bid = blockIdx.x;        // NB * 576 (4 ct * 144 ptile per b)
  const int bb = bid / 576;
  const int r2 = bid - bb * 576;
  const int ct = r2 / 144;
  const int ptile = r2 - ct * 144;
  const int c0 = ct * 64, p0 = ptile * 64;
  const float* xb = x + ((size_t)((b0 + bb) * 256 + c0)) * 9216 + p0;
#pragma unroll
  for (int i = 0; i < 16; ++i) {
    int idx = i * 256 + tid;
    int c = idx >> 6, p = idx & 63;
    Lt[c][p] = (short)f2b(xb[(size_t)c * 9216 + p]);
  }
  __syncthreads();
  unsigned short* xto = xt + ((size_t)bb * 9216 + p0) * 256 + c0;
#pragma unroll
  for (int i = 0; i < 2; ++i) {
    int t = i * 256 + tid;             // 0..511
    int p = t & 63, oc = t >> 6;       // oc 0..7
    bf16x8 v8;
#pragma unroll
    for (int e = 0; e < 8; ++e) v8[e] = Lt[oc * 8 + e][p];
    *(bf16x8*)&xto[(size_t)p * 256 + oc * 8] = v8;
  }
}

// ---------------- k_qkv: dense GEMM qkv[p][o] = xt[p][c] @ W^T, streaming --------
__global__ void __launch_bounds__(256, 4)
k_qkv(const unsigned short* __restrict__ w_bf, const unsigned short* __restrict__ xt,
      unsigned short* __restrict__ qkv) {
  const int tid = threadIdx.x;
  const int N = gridDim.x;           // NB*432, %8==0
  const int lg = (blockIdx.x & 7) * (N >> 3) + (blockIdx.x >> 3);
  const int pt = lg / 6;             // 6 consecutive logicals share p-tile (XCD L2)
  const int ot = lg - pt * 6;
  const int o0 = ot * 128;
  const int wv = tid >> 6, lane = tid & 63, ln = lane & 15, qq = lane >> 4;
  const int ow = (wv >> 1) * 64, pw = (wv & 1) * 64;
  const size_t prow = (size_t)pt * 128 + pw;
  const unsigned short* xbase = xt + (prow + ln) * 256;
  const unsigned short* wbase = w_bf + (size_t)(o0 + ow + ln) * 256;

  f32x4 acc[4][4];
#pragma unroll
  for (int mf = 0; mf < 4; ++mf)
#pragma unroll
    for (int nf = 0; nf < 4; ++nf) acc[mf][nf] = {0.f, 0.f, 0.f, 0.f};

  for (int ks = 0; ks < 8; ++ks) {
    const int co = ks * 32 + qq * 8;
    bf16x8 bfr[4], afr[4];
#pragma unroll
    for (int nf = 0; nf < 4; ++nf) bfr[nf] = *(const bf16x8*)&xbase[(size_t)nf * 4096 + co];
#pragma unroll
    for (int mf = 0; mf < 4; ++mf) afr[mf] = *(const bf16x8*)&wbase[(size_t)mf * 4096 + co];
#pragma unroll
    for (int mf = 0; mf < 4; ++mf)
#pragma unroll
      for (int nf = 0; nf < 4; ++nf)
        acc[mf][nf] = __builtin_amdgcn_mfma_f32_16x16x32_bf16(afr[mf], bfr[nf], acc[mf][nf], 0, 0, 0);
  }
#pragma unroll
  for (int mf = 0; mf < 4; ++mf)
#pragma unroll
    for (int nf = 0; nf < 4; ++nf) {
      bf16x4 sv;
#pragma unroll
      for (int r = 0; r < 4; ++r) sv[r] = (short)f2b(acc[mf][nf][r]);
      *(bf16x4*)&qkv[(prow + nf * 16 + ln) * 768 + o0 + ow + mf * 16 + qq * 4] = sv;
    }
}

// ---------------- k_attn: per-window 10-token attention + LN/GELU ----------------
__global__ void __launch_bounds__(256, 3)
k_attn(const unsigned short* __restrict__ qkv, const unsigned short* __restrict__ tok_b,
       const float* __restrict__ ln_g, const float* __restrict__ ln_b,
       unsigned short* __restrict__ t_b, unsigned short* __restrict__ gf_t, int b0) {
  __shared__ __align__(16) short smem[23040];   // vt[512][40] @0, pl[4][16][40] @20480
  short* vt = smem;
  short* pl = smem + 20480;

  const int tid = threadIdx.x;
  const int N = gridDim.x;            // NB*512, %8==0
  const int lg = (blockIdx.x & 7) * (N >> 3) + (blockIdx.x >> 3);
  const int bb = lg >> 9;
  const int b  = b0 + bb;
  const int n0 = (lg & 511) * 2;
  const int wv = tid >> 6, lane = tid & 63, ln = lane & 15, qq = lane >> 4;
  const int grp = wv >> 1;
  const int n = n0 + grp;
  const size_t brow = (size_t)bb * 9216;

  {
    bf16x8 z8 = {0, 0, 0, 0, 0, 0, 0, 0};
    for (int i = 0; i < 12; ++i) {
      int off = (i * 256 + tid) * 8;
      if (off < 23040) *(bf16x8*)&smem[off] = z8;
    }
  }
  __syncthreads();

  for (int it = 0; it < 9; ++it) {
    int t = it * 256 + tid;
    if (t < 2304) {
      int win = t >= 1152 ? 1 : 0;
      int rem = t - win * 1152;
      int pix = rem >> 7, dp = rem & 127, d = dp * 2;
      int nn = n0 + win;
      int gx = nn >> 5, gy = nn & 31;
      int gi = (pix * 11) >> 5, gj = pix - 3 * gi;
      int p = (gx * 3 + gi) * 96 + gy * 3 + gj;
      unsigned int u = *(const unsigned int*)&qkv[(brow + p) * 768 + 512 + d];
      int col = pix + 1;
      int r0 = (win << 8) + d;
      vt[r0 * 40 + swc(r0, col)] = (short)(u & 0xffffu);
      vt[(r0 + 1) * 40 + swc(r0 + 1, col)] = (short)(u >> 16);
    }
  }
#pragma unroll
  for (int i = 0; i < 2; ++i) {
    int t = i * 256 + tid;
    vt[t * 40 + swc(t, 0)] = (short)tok_b[512 + (t & 255)];
  }
  __syncthreads();

  const unsigned short* rowq;
  {
    bool isPix = (ln >= 1 && ln <= 9);
    int pix = ln - 1;
    int gi = isPix ? ((pix * 11) >> 5) : 0;
    int gj = isPix ? (pix - 3 * gi) : 0;
    int gx = n >> 5, gy = n & 31;
    int p = (gx * 3 + gi) * 96 + gy * 3 + gj;
    rowq = isPix ? qkv + (brow + p) * 768 + qq * 8 : tok_b + qq * 8;
  }

  f32x4 z = {0.f, 0.f, 0.f, 0.f};
  for (int tt = 0; tt < 4; ++tt) {
    int hh = (wv & 1) * 4 + tt;
    bf16x8 aq = *(const bf16x8*)&rowq[hh * 32];
    bf16x8 bk = *(const bf16x8*)&rowq[256 + hh * 32];
    f32x4 s = __builtin_amdgcn_mfma_f32_16x16x32_bf16(aq, bk, z, 0, 0, 0);

    float pr[4], sm[4];
#pragma unroll
    for (int r = 0; r < 4; ++r) {
      float sv = s[r] * kScale;
      if (ln >= 10) sv = -1e30f;
      float mx = sv;
#pragma unroll
      for (int d = 1; d < 16; d <<= 1) mx = fmaxf(mx, __shfl_xor(mx, d));
      pr[r] = __expf(sv - mx);
      float t2 = pr[r];
#pragma unroll
      for (int d = 1; d < 16; d <<= 1) t2 += __shfl_xor(t2, d);
      sm[r] = t2;
    }
#pragma unroll
    for (int r = 0; r < 4; ++r)
      pl[wv * 640 + (qq * 4 + r) * 40 + ln] = (short)f2b(pr[r]);

    bf16x8 ap = *(const bf16x8*)&pl[wv * 640 + ln * 40 + qq * 8];
    int rv0 = (grp << 8) + hh * 32 + ln;
    int rv1 = rv0 + 16;
    bf16x8 v0 = *(const bf16x8*)&vt[rv0 * 40 + swc(rv0, qq * 8)];
    bf16x8 v1 = *(const bf16x8*)&vt[rv1 * 40 + swc(rv1, qq * 8)];
    f32x4 o0 = __builtin_amdgcn_mfma_f32_16x16x32_bf16(ap, v0, z, 0, 0, 0);
    f32x4 o1 = __builtin_amdgcn_mfma_f32_16x16x32_bf16(ap, v1, z, 0, 0, 0);

    if (qq == 0) {
      float inv0 = 1.f / sm[0];
      float va = o0[0] * inv0, vb = o1[0] * inv0;
      float ssum = va + vb;
#pragma unroll
      for (int d = 1; d < 16; d <<= 1) ssum += __shfl_xor(ssum, d);
      float mu = ssum * (1.f / 32.f);
      float dva = va - mu, dvb = vb - mu;
      float vsum = dva * dva + dvb * dvb;
#pragma unroll
      for (int d = 1; d < 16; d <<= 1) vsum += __shfl_xor(vsum, d);
      float ri = rsqrtf(vsum * (1.f / 32.f) + 1e-5f);
      float g0 = dva * ri * ln_g[ln] + ln_b[ln];
      float g1 = dvb * ri * ln_g[16 + ln] + ln_b[16 + ln];
      float e0 = 0.5f * g0 * (1.f + erff(g0 * 0.70710678118654752f));
      float e1 = 0.5f * g1 * (1.f + erff(g1 * 0.70710678118654752f));
      size_t tb = ((size_t)(b * 1024 + n)) * 256 + hh * 32 + ln;
      t_b[tb] = f2b(e0);
      t_b[tb + 16] = f2b(e1);
    }
#pragma unroll
    for (int r = 0; r < 4; ++r) {
      int i = qq * 4 + r;
      if (i >= 1 && i <= 9) {
        float inv = 1.f / sm[r];
        size_t base = ((size_t)((b * 8 + hh) * 288) + (i - 1) * 32 + ln) * 1024 + n;
        gf_t[base] = f2b(o0[r] * inv);
        gf_t[base + 16 * 1024] = f2b(o1[r] * inv);
      }
    }
  }
}

// ---------------- k_qk: MFMA qk = w_qk(hi+lo bf16) @ t + b_qk -------------------
// Block: (b,h,ntile 256). 4 waves x 64 n. A = w_qk rows (64 e), B = t rows, K=256.
// 8 h-blocks of same (b,nt) consecutive per XCD -> t tile L2-shared.
__global__ void __launch_bounds__(256, 4)
k_qk(const unsigned short* __restrict__ t_b, const unsigned short* __restrict__ wqk_hi,
     const unsigned short* __restrict__ wqk_lo, const float* __restrict__ b_qk,
     unsigned short* __restrict__ wq_b, unsigned short* __restrict__ wk_b) {
  const int tid = threadIdx.x;
  const int bid = blockIdx.x;          // 512
  const int lg = (bid & 7) * 64 + (bid >> 3);
  const int h = lg & 7;
  const int bnt = lg >> 3;             // 0..63
  const int b = bnt >> 2, nt = bnt & 3;
  const int wv = tid >> 6, lane = tid & 63, ln = lane & 15, qq = lane >> 4;
  const int n0 = nt * 256 + wv * 64;
  const unsigned short* tb  = t_b + ((size_t)b * 1024 + n0 + ln) * 256;
  const unsigned short* whb = wqk_hi + (size_t)(h * 64 + ln) * 256;
  const unsigned short* wlb = wqk_lo + (size_t)(h * 64 + ln) * 256;

  f32x4 acc[4][4];
#pragma unroll
  for (int mf = 0; mf < 4; ++mf)
#pragma unroll
    for (int nf = 0; nf < 4; ++nf) acc[mf][nf] = {0.f, 0.f, 0.f, 0.f};

  for (int ks = 0; ks < 8; ++ks) {
    const int co = ks * 32 + qq * 8;
    bf16x8 bfr[4];
#pragma unroll
    for (int nf = 0; nf < 4; ++nf) bfr[nf] = *(const bf16x8*)&tb[(size_t)nf * 4096 + co];
#pragma unroll
    for (int mf = 0; mf < 4; ++mf) {
      bf16x8 ah = *(const bf16x8*)&whb[(size_t)mf * 4096 + co];
      bf16x8 al = *(const bf16x8*)&wlb[(size_t)mf * 4096 + co];
#pragma unroll
      for (int nf = 0; nf < 4; ++nf) {
        acc[mf][nf] = __builtin_amdgcn_mfma_f32_16x16x32_bf16(ah, bfr[nf], acc[mf][nf], 0, 0, 0);
        acc[mf][nf] = __builtin_amdgcn_mfma_f32_16x16x32_bf16(al, bfr[nf], acc[mf][nf], 0, 0, 0);
      }
    }
  }
#pragma unroll
  for (int mf = 0; mf < 4; ++mf)
#pragma unroll
    for (int r = 0; r < 4; ++r) {
      int e = mf * 16 + qq * 4 + r;
      float bias = b_qk[h * 64 + e];
#pragma unroll
      for (int nf = 0; nf < 4; ++nf) {
        int n = n0 + nf * 16 + ln;
        float v = acc[mf][nf][r] + bias;
        size_t idx = (((size_t)b * kNH + h) * kNG + n) * 32;
        if (e < 32) wq_b[idx + e] = f2b(v * kScale);
        else        wk_b[idx + (e - 32)] = f2b(v);
      }
    }
}

// ---------------- k3: barrier-free MFMA flash attention --------------------------
// Wave owns 16 q-rows x ALL 288 d (accv[18]). K frags + V frags direct from global
// (L2-hot via XCD swizzle; gf_t pre-transposed so V^T frag = contiguous 16B/lane).
// P transpose via wave-PRIVATE 1.25KB LDS patch (wave-internal lgkmcnt only).
// Zero __syncthreads in the whole kernel. T13 defer-max skips most rescales.
__global__ void __launch_bounds__(256, 4)
k_flash(const unsigned short* __restrict__ wq_b, const unsigned short* __restrict__ wk_b,
        const unsigned short* __restrict__ gf_t, unsigned short* __restrict__ agg_b) {
  __shared__ __align__(16) short pl[4 * 640];   // per-wave [16][40]

  const int tid = threadIdx.x;
  const int bid0 = blockIdx.x;   // 128 bh * 16 qtiles
  const int xcd = bid0 & 7;
  const int s   = bid0 >> 3;
  const int bh  = xcd + 8 * (s >> 4);
  const int qt  = s & 15;
  const int wv = tid >> 6, lane = tid & 63, ln = lane & 15, qq = lane >> 4;
  short* plw = pl + wv * 640;

  bf16x8 aq = *(const bf16x8*)&wq_b[(size_t)(bh * 1024 + qt * 64 + wv * 16 + ln) * 32 + qq * 8];
  const unsigned short* kb = wk_b + (size_t)bh * 32768;
  const unsigned short* vb = gf_t + (size_t)bh * 294912 + (size_t)ln * 1024;

  f32x4 accv[18];
#pragma unroll
  for (int nf = 0; nf < 18; ++nf) accv[nf] = {0.f, 0.f, 0.f, 0.f};
  float mrow[4], lrow[4];
#pragma unroll
  for (int r = 0; r < 4; ++r) { mrow[r] = -1e30f; lrow[r] = 0.f; }

  for (int kt = 0; kt < 32; ++kt) {
    const unsigned short* kp = kb + (kt * 32 + ln) * 32 + qq * 8;
    bf16x8 kf0 = *(const bf16x8*)kp;
    bf16x8 kf1 = *(const bf16x8*)(kp + 512);
    f32x4 z = {0.f, 0.f, 0.f, 0.f};
    f32x4 s0v = __builtin_amdgcn_mfma_f32_16x16x32_bf16(aq, kf0, z, 0, 0, 0);
    f32x4 s1v = __builtin_amdgcn_mfma_f32_16x16x32_bf16(aq, kf1, z, 0, 0, 0);

    float tmx[4];
    bool small = true;
#pragma unroll
    for (int r = 0; r < 4; ++r) {
      float tm = fmaxf(s0v[r], s1v[r]);
#pragma unroll
      for (int d = 1; d < 16; d <<= 1) tm = fmaxf(tm, __shfl_xor(tm, d));
      tmx[r] = tm;
      small = small && (tm - mrow[r] <= 8.f);
    }
    if (__all(small)) {
      // defer-max: keep old m, no rescale (p bounded by e^8)
#pragma unroll
      for (int r = 0; r < 4; ++r) {
        float p0 = __expf(s0v[r] - mrow[r]), p1 = __expf(s1v[r] - mrow[r]);
        float ts = p0 + p1;
#pragma unroll
        for (int d = 1; d < 16; d <<= 1) ts += __shfl_xor(ts, d);
        lrow[r] += ts;
        plw[(qq * 4 + r) * 40 + ln] = (short)f2b(p0);
        plw[(qq * 4 + r) * 40 + 16 + ln] = (short)f2b(p1);
      }
    } else {
      float alr[4];
#pragma unroll
      for (int r = 0; r < 4; ++r) {
        float nm = fmaxf(mrow[r], tmx[r]);
        alr[r] = __expf(mrow[r] - nm);
        mrow[r] = nm;
        float p0 = __expf(s0v[r] - nm), p1 = __expf(s1v[r] - nm);
        float ts = p0 + p1;
#pragma unroll
        for (int d = 1; d < 16; d <<= 1) ts += __shfl_xor(ts, d);
        lrow[r] = lrow[r] * alr[r] + ts;
        plw[(qq * 4 + r) * 40 + ln] = (short)f2b(p0);
        plw[(qq * 4 + r) * 40 + 16 + ln] = (short)f2b(p1);
      }
#pragma unroll
      for (int nf = 0; nf < 18; ++nf)
#pragma unroll
        for (int r = 0; r < 4; ++r) accv[nf][r] *= alr[r];
    }

    bf16x8 ap = *(const bf16x8*)&plw[ln * 40 + qq * 8];
    const unsigned short* vp = vb + kt * 32 + qq * 8;
    __builtin_amdgcn_s_setprio(1);
#pragma unroll
    for (int nf = 0; nf < 18; ++nf) {
      bf16x8 vf = *(const bf16x8*)&vp[(size_t)nf * 16384];
      accv[nf] = __builtin_amdgcn_mfma_f32_16x16x32_bf16(ap, vf, accv[nf], 0, 0, 0);
    }
    __builtin_amdgcn_s_setprio(0);
  }
  // epilogue: own rows only
#pragma unroll
  for (int r = 0; r < 4; ++r) {
    float linv = 1.f / lrow[r];
    int row = qt * 64 + wv * 16 + qq * 4 + r;
#pragma unroll
    for (int nf = 0; nf < 18; ++nf)
      agg_b[((size_t)bh * 1024 + row) * 288 + nf * 16 + ln] = f2b(accv[nf][r] * linv);
  }
}

// ---------------- k4: out = w_out(256x256) @ fmap + b_out, MFMA version ----------
__global__ void __launch_bounds__(256, 2)
k_out(const unsigned short* __restrict__ agg_b,
      const unsigned short* __restrict__ w_hi, const unsigned short* __restrict__ w_lo,
      const float* __restrict__ b_out, float* __restrict__ out) {
  const int tid = threadIdx.x;
  const int bid = blockIdx.x;        // 16 b * 144 ptiles
  const int b = bid / 144;
  const int pt = bid - b * 144;
  const int p_base = pt * 64;
  const int wv = tid >> 6, lane = tid & 63, ln = lane & 15, qq = lane >> 4;
  const int obase = wv * 64;

  size_t vbase[4];
#pragma unroll
  for (int nf = 0; nf < 4; ++nf) {
    int p = p_base + nf * 16 + ln;
    int hh2 = p / 96, ww2 = p - hh2 * 96;
    int xg = hh2 / 3, gi = hh2 - xg * 3;
    int yg = ww2 / 3, gj = ww2 - yg * 3;
    int nn = xg * 32 + yg, w = gi * 3 + gj;
    vbase[nf] = ((size_t)b * 8 * 1024 + nn) * 288 + w * 32 + qq * 8;
  }

  f32x4 acc[4][4];
#pragma unroll
  for (int mf = 0; mf < 4; ++mf)
#pragma unroll
    for (int nf = 0; nf < 4; ++nf) acc[mf][nf] = {0.f, 0.f, 0.f, 0.f};

  for (int ks = 0; ks < 8; ++ks) {   // ks == h
    bf16x8 bfr[4];
#pragma unroll
    for (int nf = 0; nf < 4; ++nf)
      bfr[nf] = *(const bf16x8*)&agg_b[vbase[nf] + (size_t)ks * 294912];  // 1024*288
#pragma unroll
    for (int mf = 0; mf < 4; ++mf) {
      int o = obase + mf * 16 + ln;
      bf16x8 ah = *(const bf16x8*)&w_hi[o * 256 + ks * 32 + qq * 8];
      bf16x8 al = *(const bf16x8*)&w_lo[o * 256 + ks * 32 + qq * 8];
#pragma unroll
      for (int nf = 0; nf < 4; ++nf) {
        acc[mf][nf] = __builtin_amdgcn_mfma_f32_16x16x32_bf16(ah, bfr[nf], acc[mf][nf], 0, 0, 0);
        acc[mf][nf] = __builtin_amdgcn_mfma_f32_16x16x32_bf16(al, bfr[nf], acc[mf][nf], 0, 0, 0);
      }
    }
  }
#pragma unroll
  for (int mf = 0; mf < 4; ++mf) {
#pragma unroll
    for (int r = 0; r < 4; ++r) {
      int o = obase + mf * 16 + qq * 4 + r;
      float bias = b_out[o];
#pragma unroll
      for (int nf = 0; nf < 4; ++nf) {
        int p = p_base + nf * 16 + ln;
        out[((size_t)b * 256 + o) * 9216 + p] = acc[mf][nf][r] + bias;
      }
    }
  }
}

extern "C" void kernel_launch(void* const* d_in, const int* in_sizes, int n_in,
                              void* d_out, int out_size, void* d_ws, size_t ws_size,
                              hipStream_t stream) {
  const float* x     = (const float*)d_in[0];
  const float* w_qkv = (const float*)d_in[1];
  const float* gtok  = (const float*)d_in[2];
  const float* ln_g  = (const float*)d_in[3];
  const float* ln_b  = (const float*)d_in[4];
  const float* w_qk  = (const float*)d_in[5];
  const float* b_qk  = (const float*)d_in[6];
  const float* w_out = (const float*)d_in[7];
  const float* b_out = (const float*)d_in[8];
  float* out = (float*)d_out;

  // layout (shorts):
  unsigned short* ws   = (unsigned short*)d_ws;
  unsigned short* w_bf = ws;                        // 196,608
  unsigned short* w_hi = ws + 196608;               // 65,536
  unsigned short* w_lo = ws + 262144;               // 65,536
  unsigned short* tok  = ws + 327680;               // 768 (+pad)
  unsigned short* t_b  = ws + 328704;               // 4,194,304
  unsigned short* wq_b = ws + 4523008;              // 4,194,304
  unsigned short* wk_b = ws + 8717312;              // 4,194,304
  unsigned short* gf_t = ws + 12911616;             // 37,748,736
  unsigned short* R    = ws + 50660352;             // qkv+xt chunks, later agg

  auto need = [](int NBv) -> size_t {
    size_t reg = (size_t)NBv * 9437184ull;          // qkv + xt per chunk
    if (reg < 37748736ull) reg = 37748736ull;       // agg alias floor
    return (50660352ull + reg) * 2ull;
  };
  int NB = 4;
  if (ws_size >= need(16)) NB = 16;
  else if (ws_size >= need(8)) NB = 8;

  unsigned short* qkv = R;
  unsigned short* xt  = R + (size_t)NB * 7077888ull;
  unsigned short* agg_b = R;
  // w_qk hi/lo live in the (dead-after-chunks) xt region; k_qk reads them
  // before k_flash overwrites R with agg (stream-ordered).
  unsigned short* wqk_hi = xt;
  unsigned short* wqk_lo = xt + 131072;

  k_wcvt<<<1024, 256, 0, stream>>>(w_qkv, w_out, w_bf, w_hi, w_lo);
  k_tok<<<3, 256, 0, stream>>>(w_qkv, gtok, tok);
  for (int c = 0; c < 16 / NB; ++c) {
    int b0 = c * NB;
    k_xt<<<NB * 576, 256, 0, stream>>>(x, xt, b0);
    k_qkv<<<NB * 432, 256, 0, stream>>>(w_bf, xt, qkv);
    k_attn<<<NB * 512, 256, 0, stream>>>(qkv, tok, ln_g, ln_b, t_b, gf_t, b0);
  }
  k_wqkcvt<<<512, 256, 0, stream>>>(w_qk, wqk_hi, wqk_lo);
  k_qk<<<512, 256, 0, stream>>>(t_b, wqk_hi, wqk_lo, b_qk, wq_b, wk_b);
  k_flash<<<2048, 256, 0, stream>>>(wq_b, wk_b, gf_t, agg_b);
  k_out<<<2304, 256, 0, stream>>>(agg_b, w_hi, w_lo, b_out, out);
}

// Round 6
// 1936.551 us; speedup vs baseline: 1.3056x; 1.3056x over previous
//
#include <hip/hip_runtime.h>
#include <cmath>

namespace {
constexpr int kNH = 8;
constexpr int kNG = 1024;   // 32*32 groups
constexpr float kScale = 0.17677669529663687f;  // 32^-0.5
}

typedef short  bf16x8 __attribute__((ext_vector_type(8)));
typedef short  bf16x4 __attribute__((ext_vector_type(4)));
typedef float  f32x4  __attribute__((ext_vector_type(4)));

__device__ __forceinline__ unsigned short f2b(float f) {
  unsigned int u = __builtin_bit_cast(unsigned int, f);
  u += 0x7fffu + ((u >> 16) & 1u);          // RNE
  return (unsigned short)(u >> 16);
}
__device__ __forceinline__ float b2f(unsigned short h) {
  unsigned int u = ((unsigned int)h) << 16;
  return __builtin_bit_cast(float, u);
}
// vt column swizzle (k_attn): spreads d-major scalar writes across banks.
__device__ __forceinline__ int swc(int row, int col) {
  return col ^ (((row >> 3) & 3) << 3);
}

// ---------------- k_wcvt: w_qkv (768x256) -> bf16; w_out (256x256) -> bf16 hi+lo ----
__global__ void __launch_bounds__(256) k_wcvt(const float* __restrict__ w_qkv,
                                              const float* __restrict__ w_out,
                                              unsigned short* __restrict__ wb,
                                              unsigned short* __restrict__ w_hi,
                                              unsigned short* __restrict__ w_lo) {
  int i = blockIdx.x * 256 + threadIdx.x;   // grid 1024 -> 262144
  if (i < 196608) {
    wb[i] = f2b(w_qkv[i]);
  } else {
    int k = i - 196608;                     // < 65536
    float v = w_out[k];
    unsigned short h = f2b(v);
    w_hi[k] = h;
    w_lo[k] = f2b(v - b2f(h));              // hi+lo ~ fp32-accurate weight
  }
}

// ---------------- k_wqkcvt: w_qk (512x256) -> bf16 hi+lo ------------------------
__global__ void __launch_bounds__(256) k_wqkcvt(const float* __restrict__ w_qk,
                                                unsigned short* __restrict__ hi,
                                                unsigned short* __restrict__ lo) {
  int i = blockIdx.x * 256 + threadIdx.x;   // grid 512 -> 131072
  float v = w_qk[i];
  unsigned short h = f2b(v);
  hi[i] = h;
  lo[i] = f2b(v - b2f(h));
}

// ---------------- k_tok: qkv of the group token (shared by ALL windows) ---------
__global__ void __launch_bounds__(256) k_tok(const float* __restrict__ w_qkv,
                                             const float* __restrict__ gtok,
                                             unsigned short* __restrict__ tok_b) {
  int o = blockIdx.x * 256 + threadIdx.x;   // grid 3 -> 768
  if (o < 768) {
    float s = 0.f;
    for (int c = 0; c < 256; ++c) s += w_qkv[o * 256 + c] * gtok[c];
    tok_b[o] = f2b(s);
  }
}

// ---------------- k_xt: x[b][c][9216] fp32 -> xt[(b-b0)*9216+p][256] bf16 --------
__global__ void __launch_bounds__(256, 2)
k_xt(const float* __restrict__ x, unsigned short* __restrict__ xt, int b0) {
  __shared__ short Lt[64][72];
  const int tid = threadIdx.x;
  const int bid = blockIdx.x;        // NB * 576 (4 ct * 144 ptile per b)
  const int bb = bid / 576;
  const int r2 = bid - bb * 576;
  const int ct = r2 / 144;
  const int ptile = r2 - ct * 144;
  const int c0 = ct * 64, p0 = ptile * 64;
  const float* xb = x + ((size_t)((b0 + bb) * 256 + c0)) * 9216 + p0;
#pragma unroll
  for (int i = 0; i < 16; ++i) {
    int idx = i * 256 + tid;
    int c = idx >> 6, p = idx & 63;
    Lt[c][p] = (short)f2b(xb[(size_t)c * 9216 + p]);
  }
  __syncthreads();
  unsigned short* xto = xt + ((size_t)bb * 9216 + p0) * 256 + c0;
#pragma unroll
  for (int i = 0; i < 2; ++i) {
    int t = i * 256 + tid;             // 0..511
    int p = t & 63, oc = t >> 6;       // oc 0..7
    bf16x8 v8;
#pragma unroll
    for (int e = 0; e < 8; ++e) v8[e] = Lt[oc * 8 + e][p];
    *(bf16x8*)&xto[(size_t)p * 256 + oc * 8] = v8;
  }
}

// ---------------- k_qkv: dense GEMM qkv[p][o] = xt[p][c] @ W^T, streaming --------
__global__ void __launch_bounds__(256, 4)
k_qkv(const unsigned short* __restrict__ w_bf, const unsigned short* __restrict__ xt,
      unsigned short* __restrict__ qkv) {
  const int tid = threadIdx.x;
  const int N = gridDim.x;           // NB*432, %8==0
  const int lg = (blockIdx.x & 7) * (N >> 3) + (blockIdx.x >> 3);
  const int pt = lg / 6;             // 6 consecutive logicals share p-tile (XCD L2)
  const int ot = lg - pt * 6;
  const int o0 = ot * 128;
  const int wv = tid >> 6, lane = tid & 63, ln = lane & 15, qq = lane >> 4;
  const int ow = (wv >> 1) * 64, pw = (wv & 1) * 64;
  const size_t prow = (size_t)pt * 128 + pw;
  const unsigned short* xbase = xt + (prow + ln) * 256;
  const unsigned short* wbase = w_bf + (size_t)(o0 + ow + ln) * 256;

  f32x4 acc[4][4];
#pragma unroll
  for (int mf = 0; mf < 4; ++mf)
#pragma unroll
    for (int nf = 0; nf < 4; ++nf) acc[mf][nf] = {0.f, 0.f, 0.f, 0.f};

  for (int ks = 0; ks < 8; ++ks) {
    const int co = ks * 32 + qq * 8;
    bf16x8 bfr[4], afr[4];
#pragma unroll
    for (int nf = 0; nf < 4; ++nf) bfr[nf] = *(const bf16x8*)&xbase[(size_t)nf * 4096 + co];
#pragma unroll
    for (int mf = 0; mf < 4; ++mf) afr[mf] = *(const bf16x8*)&wbase[(size_t)mf * 4096 + co];
#pragma unroll
    for (int mf = 0; mf < 4; ++mf)
#pragma unroll
      for (int nf = 0; nf < 4; ++nf)
        acc[mf][nf] = __builtin_amdgcn_mfma_f32_16x16x32_bf16(afr[mf], bfr[nf], acc[mf][nf], 0, 0, 0);
  }
#pragma unroll
  for (int mf = 0; mf < 4; ++mf)
#pragma unroll
    for (int nf = 0; nf < 4; ++nf) {
      bf16x4 sv;
#pragma unroll
      for (int r = 0; r < 4; ++r) sv[r] = (short)f2b(acc[mf][nf][r]);
      *(bf16x4*)&qkv[(prow + nf * 16 + ln) * 768 + o0 + ow + mf * 16 + qq * 4] = sv;
    }
}

// ---------------- k_attn: per-window 10-token attention + LN/GELU ----------------
__global__ void __launch_bounds__(256, 3)
k_attn(const unsigned short* __restrict__ qkv, const unsigned short* __restrict__ tok_b,
       const float* __restrict__ ln_g, const float* __restrict__ ln_b,
       unsigned short* __restrict__ t_b, unsigned short* __restrict__ gf_t, int b0) {
  __shared__ __align__(16) short smem[23040];   // vt[512][40] @0, pl[4][16][40] @20480
  short* vt = smem;
  short* pl = smem + 20480;

  const int tid = threadIdx.x;
  const int N = gridDim.x;            // NB*512, %8==0
  const int lg = (blockIdx.x & 7) * (N >> 3) + (blockIdx.x >> 3);
  const int bb = lg >> 9;
  const int b  = b0 + bb;
  const int n0 = (lg & 511) * 2;
  const int wv = tid >> 6, lane = tid & 63, ln = lane & 15, qq = lane >> 4;
  const int grp = wv >> 1;
  const int n = n0 + grp;
  const size_t brow = (size_t)bb * 9216;

  {
    bf16x8 z8 = {0, 0, 0, 0, 0, 0, 0, 0};
    for (int i = 0; i < 12; ++i) {
      int off = (i * 256 + tid) * 8;
      if (off < 23040) *(bf16x8*)&smem[off] = z8;
    }
  }
  __syncthreads();

  for (int it = 0; it < 9; ++it) {
    int t = it * 256 + tid;
    if (t < 2304) {
      int win = t >= 1152 ? 1 : 0;
      int rem = t - win * 1152;
      int pix = rem >> 7, dp = rem & 127, d = dp * 2;
      int nn = n0 + win;
      int gx = nn >> 5, gy = nn & 31;
      int gi = (pix * 11) >> 5, gj = pix - 3 * gi;
      int p = (gx * 3 + gi) * 96 + gy * 3 + gj;
      unsigned int u = *(const unsigned int*)&qkv[(brow + p) * 768 + 512 + d];
      int col = pix + 1;
      int r0 = (win << 8) + d;
      vt[r0 * 40 + swc(r0, col)] = (short)(u & 0xffffu);
      vt[(r0 + 1) * 40 + swc(r0 + 1, col)] = (short)(u >> 16);
    }
  }
#pragma unroll
  for (int i = 0; i < 2; ++i) {
    int t = i * 256 + tid;
    vt[t * 40 + swc(t, 0)] = (short)tok_b[512 + (t & 255)];
  }
  __syncthreads();

  const unsigned short* rowq;
  {
    bool isPix = (ln >= 1 && ln <= 9);
    int pix = ln - 1;
    int gi = isPix ? ((pix * 11) >> 5) : 0;
    int gj = isPix ? (pix - 3 * gi) : 0;
    int gx = n >> 5, gy = n & 31;
    int p = (gx * 3 + gi) * 96 + gy * 3 + gj;
    rowq = isPix ? qkv + (brow + p) * 768 + qq * 8 : tok_b + qq * 8;
  }

  f32x4 z = {0.f, 0.f, 0.f, 0.f};
  for (int tt = 0; tt < 4; ++tt) {
    int hh = (wv & 1) * 4 + tt;
    bf16x8 aq = *(const bf16x8*)&rowq[hh * 32];
    bf16x8 bk = *(const bf16x8*)&rowq[256 + hh * 32];
    f32x4 s = __builtin_amdgcn_mfma_f32_16x16x32_bf16(aq, bk, z, 0, 0, 0);

    float pr[4], sm[4];
#pragma unroll
    for (int r = 0; r < 4; ++r) {
      float sv = s[r] * kScale;
      if (ln >= 10) sv = -1e30f;
      float mx = sv;
#pragma unroll
      for (int d = 1; d < 16; d <<= 1) mx = fmaxf(mx, __shfl_xor(mx, d));
      pr[r] = __expf(sv - mx);
      float t2 = pr[r];
#pragma unroll
      for (int d = 1; d < 16; d <<= 1) t2 += __shfl_xor(t2, d);
      sm[r] = t2;
    }
#pragma unroll
    for (int r = 0; r < 4; ++r)
      pl[wv * 640 + (qq * 4 + r) * 40 + ln] = (short)f2b(pr[r]);

    bf16x8 ap = *(const bf16x8*)&pl[wv * 640 + ln * 40 + qq * 8];
    int rv0 = (grp << 8) + hh * 32 + ln;
    int rv1 = rv0 + 16;
    bf16x8 v0 = *(const bf16x8*)&vt[rv0 * 40 + swc(rv0, qq * 8)];
    bf16x8 v1 = *(const bf16x8*)&vt[rv1 * 40 + swc(rv1, qq * 8)];
    f32x4 o0 = __builtin_amdgcn_mfma_f32_16x16x32_bf16(ap, v0, z, 0, 0, 0);
    f32x4 o1 = __builtin_amdgcn_mfma_f32_16x16x32_bf16(ap, v1, z, 0, 0, 0);

    if (qq == 0) {
      float inv0 = 1.f / sm[0];
      float va = o0[0] * inv0, vb = o1[0] * inv0;
      float ssum = va + vb;
#pragma unroll
      for (int d = 1; d < 16; d <<= 1) ssum += __shfl_xor(ssum, d);
      float mu = ssum * (1.f / 32.f);
      float dva = va - mu, dvb = vb - mu;
      float vsum = dva * dva + dvb * dvb;
#pragma unroll
      for (int d = 1; d < 16; d <<= 1) vsum += __shfl_xor(vsum, d);
      float ri = rsqrtf(vsum * (1.f / 32.f) + 1e-5f);
      float g0 = dva * ri * ln_g[ln] + ln_b[ln];
      float g1 = dvb * ri * ln_g[16 + ln] + ln_b[16 + ln];
      float e0 = 0.5f * g0 * (1.f + erff(g0 * 0.70710678118654752f));
      float e1 = 0.5f * g1 * (1.f + erff(g1 * 0.70710678118654752f));
      size_t tb = ((size_t)(b * 1024 + n)) * 256 + hh * 32 + ln;
      t_b[tb] = f2b(e0);
      t_b[tb + 16] = f2b(e1);
    }
#pragma unroll
    for (int r = 0; r < 4; ++r) {
      int i = qq * 4 + r;
      if (i >= 1 && i <= 9) {
        float inv = 1.f / sm[r];
        size_t base = ((size_t)((b * 8 + hh) * 288) + (i - 1) * 32 + ln) * 1024 + n;
        gf_t[base] = f2b(o0[r] * inv);
        gf_t[base + 16 * 1024] = f2b(o1[r] * inv);
      }
    }
  }
}

// ---------------- k_qk: MFMA qk = w_qk(hi+lo bf16) @ t + b_qk -------------------
__global__ void __launch_bounds__(256, 4)
k_qk(const unsigned short* __restrict__ t_b, const unsigned short* __restrict__ wqk_hi,
     const unsigned short* __restrict__ wqk_lo, const float* __restrict__ b_qk,
     unsigned short* __restrict__ wq_b, unsigned short* __restrict__ wk_b) {
  const int tid = threadIdx.x;
  const int bid = blockIdx.x;          // 512
  const int lg = (bid & 7) * 64 + (bid >> 3);
  const int h = lg & 7;
  const int bnt = lg >> 3;             // 0..63
  const int b = bnt >> 2, nt = bnt & 3;
  const int wv = tid >> 6, lane = tid & 63, ln = lane & 15, qq = lane >> 4;
  const int n0 = nt * 256 + wv * 64;
  const unsigned short* tb  = t_b + ((size_t)b * 1024 + n0 + ln) * 256;
  const unsigned short* whb = wqk_hi + (size_t)(h * 64 + ln) * 256;
  const unsigned short* wlb = wqk_lo + (size_t)(h * 64 + ln) * 256;

  f32x4 acc[4][4];
#pragma unroll
  for (int mf = 0; mf < 4; ++mf)
#pragma unroll
    for (int nf = 0; nf < 4; ++nf) acc[mf][nf] = {0.f, 0.f, 0.f, 0.f};

  for (int ks = 0; ks < 8; ++ks) {
    const int co = ks * 32 + qq * 8;
    bf16x8 bfr[4];
#pragma unroll
    for (int nf = 0; nf < 4; ++nf) bfr[nf] = *(const bf16x8*)&tb[(size_t)nf * 4096 + co];
#pragma unroll
    for (int mf = 0; mf < 4; ++mf) {
      bf16x8 ah = *(const bf16x8*)&whb[(size_t)mf * 4096 + co];
      bf16x8 al = *(const bf16x8*)&wlb[(size_t)mf * 4096 + co];
#pragma unroll
      for (int nf = 0; nf < 4; ++nf) {
        acc[mf][nf] = __builtin_amdgcn_mfma_f32_16x16x32_bf16(ah, bfr[nf], acc[mf][nf], 0, 0, 0);
        acc[mf][nf] = __builtin_amdgcn_mfma_f32_16x16x32_bf16(al, bfr[nf], acc[mf][nf], 0, 0, 0);
      }
    }
  }
#pragma unroll
  for (int mf = 0; mf < 4; ++mf)
#pragma unroll
    for (int r = 0; r < 4; ++r) {
      int e = mf * 16 + qq * 4 + r;
      float bias = b_qk[h * 64 + e];
#pragma unroll
      for (int nf = 0; nf < 4; ++nf) {
        int n = n0 + nf * 16 + ln;
        float v = acc[mf][nf][r] + bias;
        size_t idx = (((size_t)b * kNH + h) * kNG + n) * 32;
        if (e < 32) wq_b[idx + e] = f2b(v * kScale);
        else        wk_b[idx + (e - 32)] = f2b(v);
      }
    }
}

// ---------------- k3: flash attention, LDS-staged V (dbuf, 1 barrier/kt) ---------
// Wave owns 16 q-rows x ALL 288 d (accv[18]); softmax wave-local w/ defer-max.
// V tile [288][40] double-buffered in LDS; tile kt+2 global loads issued during
// iter kt into ping-pong reg sets (T14); one __syncthreads per kt.
__global__ void __launch_bounds__(256, 3)
k_flash(const unsigned short* __restrict__ wq_b, const unsigned short* __restrict__ wk_b,
        const unsigned short* __restrict__ gf_t, unsigned short* __restrict__ agg_b) {
  __shared__ __align__(16) short vt[2][11520];   // [288][40] per buffer
  __shared__ __align__(16) short pl[4 * 640];    // per-wave [16][40]

  const int tid = threadIdx.x;
  const int bid0 = blockIdx.x;   // 128 bh * 16 qtiles
  const int xcd = bid0 & 7;
  const int s   = bid0 >> 3;
  const int bh  = xcd + 8 * (s >> 4);   // 16 qt of same bh consecutive per XCD
  const int qt  = s & 15;
  const int wv = tid >> 6, lane = tid & 63, ln = lane & 15, qq = lane >> 4;
  short* plw = pl + wv * 640;

  bf16x8 aq = *(const bf16x8*)&wq_b[(size_t)(bh * 1024 + qt * 64 + wv * 16 + ln) * 32 + qq * 8];
  const unsigned short* kb = wk_b + (size_t)bh * 32768;
  const unsigned short* gv = gf_t + (size_t)bh * 294912;

  // staging geometry: 1152 chunks of 8 shorts; thread covers 5 (last partial)
  const int i4 = 4 * 256 + tid;
  const bool v4 = (i4 < 1152);
  int sd[5], sc[5];
#pragma unroll
  for (int ii = 0; ii < 5; ++ii) {
    int i = ii * 256 + tid;
    sd[ii] = i >> 2;          // d row 0..287
    sc[ii] = (i & 3) * 8;     // col chunk
  }
  bf16x8 srA[5], srB[5];

#define LOAD_SET(SET, KTN)                                                        \
  {                                                                               \
    _Pragma("unroll")                                                             \
    for (int ii = 0; ii < 4; ++ii)                                                \
      SET[ii] = *(const bf16x8*)&gv[(size_t)sd[ii] * 1024 + (KTN) * 32 + sc[ii]]; \
    if (v4) SET[4] = *(const bf16x8*)&gv[(size_t)sd[4] * 1024 + (KTN) * 32 + sc[4]]; \
  }
#define WRITE_SET(SET, BUF)                                                       \
  {                                                                               \
    _Pragma("unroll")                                                             \
    for (int ii = 0; ii < 4; ++ii)                                                \
      *(bf16x8*)&vt[BUF][sd[ii] * 40 + sc[ii]] = SET[ii];                         \
    if (v4) *(bf16x8*)&vt[BUF][sd[4] * 40 + sc[4]] = SET[4];                      \
  }

  f32x4 accv[18];
#pragma unroll
  for (int nf = 0; nf < 18; ++nf) accv[nf] = {0.f, 0.f, 0.f, 0.f};
  float mrow[4], lrow[4];
#pragma unroll
  for (int r = 0; r < 4; ++r) { mrow[r] = -1e30f; lrow[r] = 0.f; }

  LOAD_SET(srA, 0);            // tile 0 (even -> A)
  WRITE_SET(srA, 0);
  LOAD_SET(srB, 1);            // tile 1 (odd -> B)
  __syncthreads();             // vt[0] visible

  for (int kt = 0; kt < 32; ++kt) {
    const int cur = kt & 1;
    // stage tile kt+1 into vt[cur^1]; issue loads for tile kt+2
    if (kt < 31) {
      if (cur == 0) { WRITE_SET(srB, 1); if (kt < 30) LOAD_SET(srA, kt + 2); }
      else          { WRITE_SET(srA, 0); if (kt < 30) LOAD_SET(srB, kt + 2); }
    }

    // QK for own 16 rows (K from global, L2-resident)
    const unsigned short* kp = kb + (kt * 32 + ln) * 32 + qq * 8;
    bf16x8 kf0 = *(const bf16x8*)kp;
    bf16x8 kf1 = *(const bf16x8*)(kp + 512);
    f32x4 z = {0.f, 0.f, 0.f, 0.f};
    f32x4 s0v = __builtin_amdgcn_mfma_f32_16x16x32_bf16(aq, kf0, z, 0, 0, 0);
    f32x4 s1v = __builtin_amdgcn_mfma_f32_16x16x32_bf16(aq, kf1, z, 0, 0, 0);

    float tmx[4];
    bool small = true;
#pragma unroll
    for (int r = 0; r < 4; ++r) {
      float tm = fmaxf(s0v[r], s1v[r]);
#pragma unroll
      for (int d = 1; d < 16; d <<= 1) tm = fmaxf(tm, __shfl_xor(tm, d));
      tmx[r] = tm;
      small = small && (tm - mrow[r] <= 8.f);
    }
    if (__all(small)) {
      // defer-max: keep old m, no rescale (p bounded by e^8)
#pragma unroll
      for (int r = 0; r < 4; ++r) {
        float p0 = __expf(s0v[r] - mrow[r]), p1 = __expf(s1v[r] - mrow[r]);
        float ts = p0 + p1;
#pragma unroll
        for (int d = 1; d < 16; d <<= 1) ts += __shfl_xor(ts, d);
        lrow[r] += ts;
        plw[(qq * 4 + r) * 40 + ln] = (short)f2b(p0);
        plw[(qq * 4 + r) * 40 + 16 + ln] = (short)f2b(p1);
      }
    } else {
      float alr[4];
#pragma unroll
      for (int r = 0; r < 4; ++r) {
        float nm = fmaxf(mrow[r], tmx[r]);
        alr[r] = __expf(mrow[r] - nm);
        mrow[r] = nm;
        float p0 = __expf(s0v[r] - nm), p1 = __expf(s1v[r] - nm);
        float ts = p0 + p1;
#pragma unroll
        for (int d = 1; d < 16; d <<= 1) ts += __shfl_xor(ts, d);
        lrow[r] = lrow[r] * alr[r] + ts;
        plw[(qq * 4 + r) * 40 + ln] = (short)f2b(p0);
        plw[(qq * 4 + r) * 40 + 16 + ln] = (short)f2b(p1);
      }
#pragma unroll
      for (int nf = 0; nf < 18; ++nf)
#pragma unroll
        for (int r = 0; r < 4; ++r) accv[nf][r] *= alr[r];
    }

    // PV from vt[cur] (staged during iter kt-1, visible via end-of-iter barrier)
    bf16x8 ap = *(const bf16x8*)&plw[ln * 40 + qq * 8];
    __builtin_amdgcn_s_setprio(1);
#pragma unroll
    for (int nf = 0; nf < 18; ++nf) {
      bf16x8 vf = *(const bf16x8*)&vt[cur][(nf * 16 + ln) * 40 + qq * 8];
      accv[nf] = __builtin_amdgcn_mfma_f32_16x16x32_bf16(ap, vf, accv[nf], 0, 0, 0);
    }
    __builtin_amdgcn_s_setprio(0);
    __syncthreads();   // PV(kt) done; writes of vt[cur^1] done -> safe for kt+1
  }
#undef LOAD_SET
#undef WRITE_SET

  // epilogue: own rows only
#pragma unroll
  for (int r = 0; r < 4; ++r) {
    float linv = 1.f / lrow[r];
    int row = qt * 64 + wv * 16 + qq * 4 + r;
#pragma unroll
    for (int nf = 0; nf < 18; ++nf)
      agg_b[((size_t)bh * 1024 + row) * 288 + nf * 16 + ln] = f2b(accv[nf][r] * linv);
  }
}

// ---------------- k4: out = w_out(256x256) @ fmap + b_out, MFMA version ----------
__global__ void __launch_bounds__(256, 2)
k_out(const unsigned short* __restrict__ agg_b,
      const unsigned short* __restrict__ w_hi, const unsigned short* __restrict__ w_lo,
      const float* __restrict__ b_out, float* __restrict__ out) {
  const int tid = threadIdx.x;
  const int bid = blockIdx.x;        // 16 b * 144 ptiles
  const int b = bid / 144;
  const int pt = bid - b * 144;
  const int p_base = pt * 64;
  const int wv = tid >> 6, lane = tid & 63, ln = lane & 15, qq = lane >> 4;
  const int obase = wv * 64;

  size_t vbase[4];
#pragma unroll
  for (int nf = 0; nf < 4; ++nf) {
    int p = p_base + nf * 16 + ln;
    int hh2 = p / 96, ww2 = p - hh2 * 96;
    int xg = hh2 / 3, gi = hh2 - xg * 3;
    int yg = ww2 / 3, gj = ww2 - yg * 3;
    int nn = xg * 32 + yg, w = gi * 3 + gj;
    vbase[nf] = ((size_t)b * 8 * 1024 + nn) * 288 + w * 32 + qq * 8;
  }

  f32x4 acc[4][4];
#pragma unroll
  for (int mf = 0; mf < 4; ++mf)
#pragma unroll
    for (int nf = 0; nf < 4; ++nf) acc[mf][nf] = {0.f, 0.f, 0.f, 0.f};

  for (int ks = 0; ks < 8; ++ks) {   // ks == h
    bf16x8 bfr[4];
#pragma unroll
    for (int nf = 0; nf < 4; ++nf)
      bfr[nf] = *(const bf16x8*)&agg_b[vbase[nf] + (size_t)ks * 294912];  // 1024*288
#pragma unroll
    for (int mf = 0; mf < 4; ++mf) {
      int o = obase + mf * 16 + ln;
      bf16x8 ah = *(const bf16x8*)&w_hi[o * 256 + ks * 32 + qq * 8];
      bf16x8 al = *(const bf16x8*)&w_lo[o * 256 + ks * 32 + qq * 8];
#pragma unroll
      for (int nf = 0; nf < 4; ++nf) {
        acc[mf][nf] = __builtin_amdgcn_mfma_f32_16x16x32_bf16(ah, bfr[nf], acc[mf][nf], 0, 0, 0);
        acc[mf][nf] = __builtin_amdgcn_mfma_f32_16x16x32_bf16(al, bfr[nf], acc[mf][nf], 0, 0, 0);
      }
    }
  }
#pragma unroll
  for (int mf = 0; mf < 4; ++mf) {
#pragma unroll
    for (int r = 0; r < 4; ++r) {
      int o = obase + mf * 16 + qq * 4 + r;
      float bias = b_out[o];
#pragma unroll
      for (int nf = 0; nf < 4; ++nf) {
        int p = p_base + nf * 16 + ln;
        out[((size_t)b * 256 + o) * 9216 + p] = acc[mf][nf][r] + bias;
      }
    }
  }
}

extern "C" void kernel_launch(void* const* d_in, const int* in_sizes, int n_in,
                              void* d_out, int out_size, void* d_ws, size_t ws_size,
                              hipStream_t stream) {
  const float* x     = (const float*)d_in[0];
  const float* w_qkv = (const float*)d_in[1];
  const float* gtok  = (const float*)d_in[2];
  const float* ln_g  = (const float*)d_in[3];
  const float* ln_b  = (const float*)d_in[4];
  const float* w_qk  = (const float*)d_in[5];
  const float* b_qk  = (const float*)d_in[6];
  const float* w_out = (const float*)d_in[7];
  const float* b_out = (const float*)d_in[8];
  float* out = (float*)d_out;

  // layout (shorts):
  unsigned short* ws   = (unsigned short*)d_ws;
  unsigned short* w_bf = ws;                        // 196,608
  unsigned short* w_hi = ws + 196608;               // 65,536
  unsigned short* w_lo = ws + 262144;               // 65,536
  unsigned short* tok  = ws + 327680;               // 768 (+pad)
  unsigned short* t_b  = ws + 328704;               // 4,194,304
  unsigned short* wq_b = ws + 4523008;              // 4,194,304
  unsigned short* wk_b = ws + 8717312;              // 4,194,304
  unsigned short* gf_t = ws + 12911616;             // 37,748,736
  unsigned short* R    = ws + 50660352;             // qkv+xt chunks, later agg

  auto need = [](int NBv) -> size_t {
    size_t reg = (size_t)NBv * 9437184ull;          // qkv + xt per chunk
    if (reg < 37748736ull) reg = 37748736ull;       // agg alias floor
    return (50660352ull + reg) * 2ull;
  };
  int NB = 4;
  if (ws_size >= need(16)) NB = 16;
  else if (ws_size >= need(8)) NB = 8;

  unsigned short* qkv = R;
  unsigned short* xt  = R + (size_t)NB * 7077888ull;
  unsigned short* agg_b = R;
  // w_qk hi/lo live in the (dead-after-chunks) xt region; k_qk reads them
  // before k_flash overwrites R with agg (stream-ordered).
  unsigned short* wqk_hi = xt;
  unsigned short* wqk_lo = xt + 131072;

  k_wcvt<<<1024, 256, 0, stream>>>(w_qkv, w_out, w_bf, w_hi, w_lo);
  k_tok<<<3, 256, 0, stream>>>(w_qkv, gtok, tok);
  for (int c = 0; c < 16 / NB; ++c) {
    int b0 = c * NB;
    k_xt<<<NB * 576, 256, 0, stream>>>(x, xt, b0);
    k_qkv<<<NB * 432, 256, 0, stream>>>(w_bf, xt, qkv);
    k_attn<<<NB * 512, 256, 0, stream>>>(qkv, tok, ln_g, ln_b, t_b, gf_t, b0);
  }
  k_wqkcvt<<<512, 256, 0, stream>>>(w_qk, wqk_hi, wqk_lo);
  k_qk<<<512, 256, 0, stream>>>(t_b, wqk_hi, wqk_lo, b_qk, wq_b, wk_b);
  k_flash<<<2048, 256, 0, stream>>>(wq_b, wk_b, gf_t, agg_b);
  k_out<<<2304, 256, 0, stream>>>(agg_b, w_hi, w_lo, b_out, out);
}

// Round 7
// 1171.221 us; speedup vs baseline: 2.1587x; 1.6534x over previous
//
#include <hip/hip_runtime.h>
#include <cmath>

namespace {
constexpr int kNH = 8;
constexpr int kNG = 1024;   // 32*32 groups
constexpr float kScale = 0.17677669529663687f;  // 32^-0.5
}

typedef short  bf16x8 __attribute__((ext_vector_type(8)));
typedef short  bf16x4 __attribute__((ext_vector_type(4)));
typedef float  f32x4  __attribute__((ext_vector_type(4)));

__device__ __forceinline__ unsigned short f2b(float f) {
  unsigned int u = __builtin_bit_cast(unsigned int, f);
  u += 0x7fffu + ((u >> 16) & 1u);          // RNE
  return (unsigned short)(u >> 16);
}
__device__ __forceinline__ float b2f(unsigned short h) {
  unsigned int u = ((unsigned int)h) << 16;
  return __builtin_bit_cast(float, u);
}
// vt column swizzle (k_attn): spreads d-major scalar writes across banks.
__device__ __forceinline__ int swc(int row, int col) {
  return col ^ (((row >> 3) & 3) << 3);
}

// ---------------- k_wcvt: w_qkv (768x256) -> bf16; w_out (256x256) -> bf16 hi+lo ----
__global__ void __launch_bounds__(256) k_wcvt(const float* __restrict__ w_qkv,
                                              const float* __restrict__ w_out,
                                              unsigned short* __restrict__ wb,
                                              unsigned short* __restrict__ w_hi,
                                              unsigned short* __restrict__ w_lo) {
  int i = blockIdx.x * 256 + threadIdx.x;   // grid 1024 -> 262144
  if (i < 196608) {
    wb[i] = f2b(w_qkv[i]);
  } else {
    int k = i - 196608;                     // < 65536
    float v = w_out[k];
    unsigned short h = f2b(v);
    w_hi[k] = h;
    w_lo[k] = f2b(v - b2f(h));              // hi+lo ~ fp32-accurate weight
  }
}

// ---------------- k_wqkcvt: w_qk (512x256) -> bf16 hi+lo ------------------------
__global__ void __launch_bounds__(256) k_wqkcvt(const float* __restrict__ w_qk,
                                                unsigned short* __restrict__ hi,
                                                unsigned short* __restrict__ lo) {
  int i = blockIdx.x * 256 + threadIdx.x;   // grid 512 -> 131072
  float v = w_qk[i];
  unsigned short h = f2b(v);
  hi[i] = h;
  lo[i] = f2b(v - b2f(h));
}

// ---------------- k_tok: qkv of the group token (shared by ALL windows) ---------
__global__ void __launch_bounds__(256) k_tok(const float* __restrict__ w_qkv,
                                             const float* __restrict__ gtok,
                                             unsigned short* __restrict__ tok_b) {
  int o = blockIdx.x * 256 + threadIdx.x;   // grid 3 -> 768
  if (o < 768) {
    float s = 0.f;
    for (int c = 0; c < 256; ++c) s += w_qkv[o * 256 + c] * gtok[c];
    tok_b[o] = f2b(s);
  }
}

// ---------------- k_xt: x[b][c][9216] fp32 -> xt[(b-b0)*9216+p][256] bf16 --------
__global__ void __launch_bounds__(256, 2)
k_xt(const float* __restrict__ x, unsigned short* __restrict__ xt, int b0) {
  __shared__ short Lt[64][72];
  const int tid = threadIdx.x;
  const int bid = blockIdx.x;        // NB * 576 (4 ct * 144 ptile per b)
  const int bb = bid / 576;
  const int r2 = bid - bb * 576;
  const int ct = r2 / 144;
  const int ptile = r2 - ct * 144;
  const int c0 = ct * 64, p0 = ptile * 64;
  const float* xb = x + ((size_t)((b0 + bb) * 256 + c0)) * 9216 + p0;
#pragma unroll
  for (int i = 0; i < 16; ++i) {
    int idx = i * 256 + tid;
    int c = idx >> 6, p = idx & 63;
    Lt[c][p] = (short)f2b(xb[(size_t)c * 9216 + p]);
  }
  __syncthreads();
  unsigned short* xto = xt + ((size_t)bb * 9216 + p0) * 256 + c0;
#pragma unroll
  for (int i = 0; i < 2; ++i) {
    int t = i * 256 + tid;             // 0..511
    int p = t & 63, oc = t >> 6;       // oc 0..7
    bf16x8 v8;
#pragma unroll
    for (int e = 0; e < 8; ++e) v8[e] = Lt[oc * 8 + e][p];
    *(bf16x8*)&xto[(size_t)p * 256 + oc * 8] = v8;
  }
}

// ---------------- k_qkv: dense GEMM qkv[p][o] = xt[p][c] @ W^T, streaming --------
__global__ void __launch_bounds__(256, 4)
k_qkv(const unsigned short* __restrict__ w_bf, const unsigned short* __restrict__ xt,
      unsigned short* __restrict__ qkv) {
  const int tid = threadIdx.x;
  const int N = gridDim.x;           // NB*432, %8==0
  const int lg = (blockIdx.x & 7) * (N >> 3) + (blockIdx.x >> 3);
  const int pt = lg / 6;             // 6 consecutive logicals share p-tile (XCD L2)
  const int ot = lg - pt * 6;
  const int o0 = ot * 128;
  const int wv = tid >> 6, lane = tid & 63, ln = lane & 15, qq = lane >> 4;
  const int ow = (wv >> 1) * 64, pw = (wv & 1) * 64;
  const size_t prow = (size_t)pt * 128 + pw;
  const unsigned short* xbase = xt + (prow + ln) * 256;
  const unsigned short* wbase = w_bf + (size_t)(o0 + ow + ln) * 256;

  f32x4 acc[4][4];
#pragma unroll
  for (int mf = 0; mf < 4; ++mf)
#pragma unroll
    for (int nf = 0; nf < 4; ++nf) acc[mf][nf] = {0.f, 0.f, 0.f, 0.f};

  for (int ks = 0; ks < 8; ++ks) {
    const int co = ks * 32 + qq * 8;
    bf16x8 bfr[4], afr[4];
#pragma unroll
    for (int nf = 0; nf < 4; ++nf) bfr[nf] = *(const bf16x8*)&xbase[(size_t)nf * 4096 + co];
#pragma unroll
    for (int mf = 0; mf < 4; ++mf) afr[mf] = *(const bf16x8*)&wbase[(size_t)mf * 4096 + co];
#pragma unroll
    for (int mf = 0; mf < 4; ++mf)
#pragma unroll
      for (int nf = 0; nf < 4; ++nf)
        acc[mf][nf] = __builtin_amdgcn_mfma_f32_16x16x32_bf16(afr[mf], bfr[nf], acc[mf][nf], 0, 0, 0);
  }
#pragma unroll
  for (int mf = 0; mf < 4; ++mf)
#pragma unroll
    for (int nf = 0; nf < 4; ++nf) {
      bf16x4 sv;
#pragma unroll
      for (int r = 0; r < 4; ++r) sv[r] = (short)f2b(acc[mf][nf][r]);
      *(bf16x4*)&qkv[(prow + nf * 16 + ln) * 768 + o0 + ow + mf * 16 + qq * 4] = sv;
    }
}

// ---------------- k_attn: per-window 10-token attention + LN/GELU ----------------
__global__ void __launch_bounds__(256, 3)
k_attn(const unsigned short* __restrict__ qkv, const unsigned short* __restrict__ tok_b,
       const float* __restrict__ ln_g, const float* __restrict__ ln_b,
       unsigned short* __restrict__ t_b, unsigned short* __restrict__ gf_t, int b0) {
  __shared__ __align__(16) short smem[23040];   // vt[512][40] @0, pl[4][16][40] @20480
  short* vt = smem;
  short* pl = smem + 20480;

  const int tid = threadIdx.x;
  const int N = gridDim.x;            // NB*512, %8==0
  const int lg = (blockIdx.x & 7) * (N >> 3) + (blockIdx.x >> 3);
  const int bb = lg >> 9;
  const int b  = b0 + bb;
  const int n0 = (lg & 511) * 2;
  const int wv = tid >> 6, lane = tid & 63, ln = lane & 15, qq = lane >> 4;
  const int grp = wv >> 1;
  const int n = n0 + grp;
  const size_t brow = (size_t)bb * 9216;

  {
    bf16x8 z8 = {0, 0, 0, 0, 0, 0, 0, 0};
    for (int i = 0; i < 12; ++i) {
      int off = (i * 256 + tid) * 8;
      if (off < 23040) *(bf16x8*)&smem[off] = z8;
    }
  }
  __syncthreads();

  for (int it = 0; it < 9; ++it) {
    int t = it * 256 + tid;
    if (t < 2304) {
      int win = t >= 1152 ? 1 : 0;
      int rem = t - win * 1152;
      int pix = rem >> 7, dp = rem & 127, d = dp * 2;
      int nn = n0 + win;
      int gx = nn >> 5, gy = nn & 31;
      int gi = (pix * 11) >> 5, gj = pix - 3 * gi;
      int p = (gx * 3 + gi) * 96 + gy * 3 + gj;
      unsigned int u = *(const unsigned int*)&qkv[(brow + p) * 768 + 512 + d];
      int col = pix + 1;
      int r0 = (win << 8) + d;
      vt[r0 * 40 + swc(r0, col)] = (short)(u & 0xffffu);
      vt[(r0 + 1) * 40 + swc(r0 + 1, col)] = (short)(u >> 16);
    }
  }
#pragma unroll
  for (int i = 0; i < 2; ++i) {
    int t = i * 256 + tid;
    vt[t * 40 + swc(t, 0)] = (short)tok_b[512 + (t & 255)];
  }
  __syncthreads();

  const unsigned short* rowq;
  {
    bool isPix = (ln >= 1 && ln <= 9);
    int pix = ln - 1;
    int gi = isPix ? ((pix * 11) >> 5) : 0;
    int gj = isPix ? (pix - 3 * gi) : 0;
    int gx = n >> 5, gy = n & 31;
    int p = (gx * 3 + gi) * 96 + gy * 3 + gj;
    rowq = isPix ? qkv + (brow + p) * 768 + qq * 8 : tok_b + qq * 8;
  }

  f32x4 z = {0.f, 0.f, 0.f, 0.f};
  for (int tt = 0; tt < 4; ++tt) {
    int hh = (wv & 1) * 4 + tt;
    bf16x8 aq = *(const bf16x8*)&rowq[hh * 32];
    bf16x8 bk = *(const bf16x8*)&rowq[256 + hh * 32];
    f32x4 s = __builtin_amdgcn_mfma_f32_16x16x32_bf16(aq, bk, z, 0, 0, 0);

    float pr[4], sm[4];
#pragma unroll
    for (int r = 0; r < 4; ++r) {
      float sv = s[r] * kScale;
      if (ln >= 10) sv = -1e30f;
      float mx = sv;
#pragma unroll
      for (int d = 1; d < 16; d <<= 1) mx = fmaxf(mx, __shfl_xor(mx, d));
      pr[r] = __expf(sv - mx);
      float t2 = pr[r];
#pragma unroll
      for (int d = 1; d < 16; d <<= 1) t2 += __shfl_xor(t2, d);
      sm[r] = t2;
    }
#pragma unroll
    for (int r = 0; r < 4; ++r)
      pl[wv * 640 + (qq * 4 + r) * 40 + ln] = (short)f2b(pr[r]);

    bf16x8 ap = *(const bf16x8*)&pl[wv * 640 + ln * 40 + qq * 8];
    int rv0 = (grp << 8) + hh * 32 + ln;
    int rv1 = rv0 + 16;
    bf16x8 v0 = *(const bf16x8*)&vt[rv0 * 40 + swc(rv0, qq * 8)];
    bf16x8 v1 = *(const bf16x8*)&vt[rv1 * 40 + swc(rv1, qq * 8)];
    f32x4 o0 = __builtin_amdgcn_mfma_f32_16x16x32_bf16(ap, v0, z, 0, 0, 0);
    f32x4 o1 = __builtin_amdgcn_mfma_f32_16x16x32_bf16(ap, v1, z, 0, 0, 0);

    if (qq == 0) {
      float inv0 = 1.f / sm[0];
      float va = o0[0] * inv0, vb = o1[0] * inv0;
      float ssum = va + vb;
#pragma unroll
      for (int d = 1; d < 16; d <<= 1) ssum += __shfl_xor(ssum, d);
      float mu = ssum * (1.f / 32.f);
      float dva = va - mu, dvb = vb - mu;
      float vsum = dva * dva + dvb * dvb;
#pragma unroll
      for (int d = 1; d < 16; d <<= 1) vsum += __shfl_xor(vsum, d);
      float ri = rsqrtf(vsum * (1.f / 32.f) + 1e-5f);
      float g0 = dva * ri * ln_g[ln] + ln_b[ln];
      float g1 = dvb * ri * ln_g[16 + ln] + ln_b[16 + ln];
      float e0 = 0.5f * g0 * (1.f + erff(g0 * 0.70710678118654752f));
      float e1 = 0.5f * g1 * (1.f + erff(g1 * 0.70710678118654752f));
      size_t tb = ((size_t)(b * 1024 + n)) * 256 + hh * 32 + ln;
      t_b[tb] = f2b(e0);
      t_b[tb + 16] = f2b(e1);
    }
#pragma unroll
    for (int r = 0; r < 4; ++r) {
      int i = qq * 4 + r;
      if (i >= 1 && i <= 9) {
        float inv = 1.f / sm[r];
        size_t base = ((size_t)((b * 8 + hh) * 288) + (i - 1) * 32 + ln) * 1024 + n;
        gf_t[base] = f2b(o0[r] * inv);
        gf_t[base + 16 * 1024] = f2b(o1[r] * inv);
      }
    }
  }
}

// ---------------- k_qk: MFMA qk = w_qk(hi+lo bf16) @ t + b_qk -------------------
__global__ void __launch_bounds__(256, 4)
k_qk(const unsigned short* __restrict__ t_b, const unsigned short* __restrict__ wqk_hi,
     const unsigned short* __restrict__ wqk_lo, const float* __restrict__ b_qk,
     unsigned short* __restrict__ wq_b, unsigned short* __restrict__ wk_b) {
  const int tid = threadIdx.x;
  const int bid = blockIdx.x;          // 512
  const int lg = (bid & 7) * 64 + (bid >> 3);
  const int h = lg & 7;
  const int bnt = lg >> 3;             // 0..63
  const int b = bnt >> 2, nt = bnt & 3;
  const int wv = tid >> 6, lane = tid & 63, ln = lane & 15, qq = lane >> 4;
  const int n0 = nt * 256 + wv * 64;
  const unsigned short* tb  = t_b + ((size_t)b * 1024 + n0 + ln) * 256;
  const unsigned short* whb = wqk_hi + (size_t)(h * 64 + ln) * 256;
  const unsigned short* wlb = wqk_lo + (size_t)(h * 64 + ln) * 256;

  f32x4 acc[4][4];
#pragma unroll
  for (int mf = 0; mf < 4; ++mf)
#pragma unroll
    for (int nf = 0; nf < 4; ++nf) acc[mf][nf] = {0.f, 0.f, 0.f, 0.f};

  for (int ks = 0; ks < 8; ++ks) {
    const int co = ks * 32 + qq * 8;
    bf16x8 bfr[4];
#pragma unroll
    for (int nf = 0; nf < 4; ++nf) bfr[nf] = *(const bf16x8*)&tb[(size_t)nf * 4096 + co];
#pragma unroll
    for (int mf = 0; mf < 4; ++mf) {
      bf16x8 ah = *(const bf16x8*)&whb[(size_t)mf * 4096 + co];
      bf16x8 al = *(const bf16x8*)&wlb[(size_t)mf * 4096 + co];
#pragma unroll
      for (int nf = 0; nf < 4; ++nf) {
        acc[mf][nf] = __builtin_amdgcn_mfma_f32_16x16x32_bf16(ah, bfr[nf], acc[mf][nf], 0, 0, 0);
        acc[mf][nf] = __builtin_amdgcn_mfma_f32_16x16x32_bf16(al, bfr[nf], acc[mf][nf], 0, 0, 0);
      }
    }
  }
#pragma unroll
  for (int mf = 0; mf < 4; ++mf)
#pragma unroll
    for (int r = 0; r < 4; ++r) {
      int e = mf * 16 + qq * 4 + r;
      float bias = b_qk[h * 64 + e];
#pragma unroll
      for (int nf = 0; nf < 4; ++nf) {
        int n = n0 + nf * 16 + ln;
        float v = acc[mf][nf][r] + bias;
        size_t idx = (((size_t)b * kNH + h) * kNG + n) * 32;
        if (e < 32) wq_b[idx + e] = f2b(v * kScale);
        else        wk_b[idx + (e - 32)] = f2b(v);
      }
    }
}

// ---------------- k3: flash attention, single-buffer LDS V, no spill -------------
// Wave owns 16 q-rows x ALL 288 d (accv[18] = 72 VGPR); softmax wave-local with
// defer-max. ONE staging register set sr[5] (loads for kt+1 issued after writing
// kt, covered by QK+softmax+PV+barriers). launch_bounds(256,2) -> VGPR cap 256,
// no scratch spill (r5/r6 failure mode: accv spilled, 2-4 GB scratch traffic).
__global__ void __launch_bounds__(256, 2)
k_flash(const unsigned short* __restrict__ wq_b, const unsigned short* __restrict__ wk_b,
        const unsigned short* __restrict__ gf_t, unsigned short* __restrict__ agg_b) {
  __shared__ __align__(16) short vt[11520];     // [288][40]
  __shared__ __align__(16) short pl[4 * 640];   // per-wave [16][40]

  const int tid = threadIdx.x;
  const int bid0 = blockIdx.x;   // 128 bh * 16 qtiles
  const int xcd = bid0 & 7;
  const int s   = bid0 >> 3;
  const int bh  = xcd + 8 * (s >> 4);   // 16 qt of same bh consecutive per XCD
  const int qt  = s & 15;
  const int wv = tid >> 6, lane = tid & 63, ln = lane & 15, qq = lane >> 4;
  short* plw = pl + wv * 640;

  bf16x8 aq = *(const bf16x8*)&wq_b[(size_t)(bh * 1024 + qt * 64 + wv * 16 + ln) * 32 + qq * 8];
  const unsigned short* kb = wk_b + (size_t)bh * 32768;
  const unsigned short* gv = gf_t + (size_t)bh * 294912;

  // staging geometry: 1152 chunks of 8 shorts; thread covers 5 (last partial)
  const bool v4 = (4 * 256 + tid) < 1152;
  int sd[5], sc[5];
#pragma unroll
  for (int ii = 0; ii < 5; ++ii) {
    int i = ii * 256 + tid;
    sd[ii] = i >> 2;          // d row 0..287
    sc[ii] = (i & 3) * 8;     // col chunk
  }
  bf16x8 sr[5];

#define LOAD_SET(KTN)                                                             \
  {                                                                               \
    _Pragma("unroll")                                                             \
    for (int ii = 0; ii < 4; ++ii)                                                \
      sr[ii] = *(const bf16x8*)&gv[(size_t)sd[ii] * 1024 + (KTN) * 32 + sc[ii]];  \
    if (v4) sr[4] = *(const bf16x8*)&gv[(size_t)sd[4] * 1024 + (KTN) * 32 + sc[4]]; \
  }
#define WRITE_SET()                                                               \
  {                                                                               \
    _Pragma("unroll")                                                             \
    for (int ii = 0; ii < 4; ++ii)                                                \
      *(bf16x8*)&vt[sd[ii] * 40 + sc[ii]] = sr[ii];                               \
    if (v4) *(bf16x8*)&vt[sd[4] * 40 + sc[4]] = sr[4];                            \
  }

  f32x4 accv[18];
#pragma unroll
  for (int nf = 0; nf < 18; ++nf) accv[nf] = {0.f, 0.f, 0.f, 0.f};
  float mrow[4], lrow[4];
#pragma unroll
  for (int r = 0; r < 4; ++r) { mrow[r] = -1e30f; lrow[r] = 0.f; }

  LOAD_SET(0);

  for (int kt = 0; kt < 32; ++kt) {
    WRITE_SET();                 // vt free (prev PV done via end barrier)
    if (kt < 31) LOAD_SET(kt + 1);

    // QK for own 16 rows (K from global, L2-resident)
    const unsigned short* kp = kb + (kt * 32 + ln) * 32 + qq * 8;
    bf16x8 kf0 = *(const bf16x8*)kp;
    bf16x8 kf1 = *(const bf16x8*)(kp + 512);
    f32x4 z = {0.f, 0.f, 0.f, 0.f};
    f32x4 s0v = __builtin_amdgcn_mfma_f32_16x16x32_bf16(aq, kf0, z, 0, 0, 0);
    f32x4 s1v = __builtin_amdgcn_mfma_f32_16x16x32_bf16(aq, kf1, z, 0, 0, 0);

    float tmx[4];
    bool small = true;
#pragma unroll
    for (int r = 0; r < 4; ++r) {
      float tm = fmaxf(s0v[r], s1v[r]);
#pragma unroll
      for (int d = 1; d < 16; d <<= 1) tm = fmaxf(tm, __shfl_xor(tm, d));
      tmx[r] = tm;
      small = small && (tm - mrow[r] <= 8.f);
    }
    if (__all(small)) {
      // defer-max: keep old m, no rescale (p bounded by e^8)
#pragma unroll
      for (int r = 0; r < 4; ++r) {
        float p0 = __expf(s0v[r] - mrow[r]), p1 = __expf(s1v[r] - mrow[r]);
        float ts = p0 + p1;
#pragma unroll
        for (int d = 1; d < 16; d <<= 1) ts += __shfl_xor(ts, d);
        lrow[r] += ts;
        plw[(qq * 4 + r) * 40 + ln] = (short)f2b(p0);
        plw[(qq * 4 + r) * 40 + 16 + ln] = (short)f2b(p1);
      }
    } else {
      float alr[4];
#pragma unroll
      for (int r = 0; r < 4; ++r) {
        float nm = fmaxf(mrow[r], tmx[r]);
        alr[r] = __expf(mrow[r] - nm);
        mrow[r] = nm;
        float p0 = __expf(s0v[r] - nm), p1 = __expf(s1v[r] - nm);
        float ts = p0 + p1;
#pragma unroll
        for (int d = 1; d < 16; d <<= 1) ts += __shfl_xor(ts, d);
        lrow[r] = lrow[r] * alr[r] + ts;
        plw[(qq * 4 + r) * 40 + ln] = (short)f2b(p0);
        plw[(qq * 4 + r) * 40 + 16 + ln] = (short)f2b(p1);
      }
#pragma unroll
      for (int nf = 0; nf < 18; ++nf)
#pragma unroll
        for (int r = 0; r < 4; ++r) accv[nf][r] *= alr[r];
    }

    __syncthreads();             // vt staged by all waves

    bf16x8 ap = *(const bf16x8*)&plw[ln * 40 + qq * 8];
    __builtin_amdgcn_s_setprio(1);
#pragma unroll
    for (int nf = 0; nf < 18; ++nf) {
      bf16x8 vf = *(const bf16x8*)&vt[(nf * 16 + ln) * 40 + qq * 8];
      accv[nf] = __builtin_amdgcn_mfma_f32_16x16x32_bf16(ap, vf, accv[nf], 0, 0, 0);
    }
    __builtin_amdgcn_s_setprio(0);
    __syncthreads();             // PV done -> vt reusable next iter
  }
#undef LOAD_SET
#undef WRITE_SET

  // epilogue: own rows only
#pragma unroll
  for (int r = 0; r < 4; ++r) {
    float linv = 1.f / lrow[r];
    int row = qt * 64 + wv * 16 + qq * 4 + r;
#pragma unroll
    for (int nf = 0; nf < 18; ++nf)
      agg_b[((size_t)bh * 1024 + row) * 288 + nf * 16 + ln] = f2b(accv[nf][r] * linv);
  }
}

// ---------------- k4: out = w_out(256x256) @ fmap + b_out, MFMA version ----------
__global__ void __launch_bounds__(256, 2)
k_out(const unsigned short* __restrict__ agg_b,
      const unsigned short* __restrict__ w_hi, const unsigned short* __restrict__ w_lo,
      const float* __restrict__ b_out, float* __restrict__ out) {
  const int tid = threadIdx.x;
  const int bid = blockIdx.x;        // 16 b * 144 ptiles
  const int b = bid / 144;
  const int pt = bid - b * 144;
  const int p_base = pt * 64;
  const int wv = tid >> 6, lane = tid & 63, ln = lane & 15, qq = lane >> 4;
  const int obase = wv * 64;

  size_t vbase[4];
#pragma unroll
  for (int nf = 0; nf < 4; ++nf) {
    int p = p_base + nf * 16 + ln;
    int hh2 = p / 96, ww2 = p - hh2 * 96;
    int xg = hh2 / 3, gi = hh2 - xg * 3;
    int yg = ww2 / 3, gj = ww2 - yg * 3;
    int nn = xg * 32 + yg, w = gi * 3 + gj;
    vbase[nf] = ((size_t)b * 8 * 1024 + nn) * 288 + w * 32 + qq * 8;
  }

  f32x4 acc[4][4];
#pragma unroll
  for (int mf = 0; mf < 4; ++mf)
#pragma unroll
    for (int nf = 0; nf < 4; ++nf) acc[mf][nf] = {0.f, 0.f, 0.f, 0.f};

  for (int ks = 0; ks < 8; ++ks) {   // ks == h
    bf16x8 bfr[4];
#pragma unroll
    for (int nf = 0; nf < 4; ++nf)
      bfr[nf] = *(const bf16x8*)&agg_b[vbase[nf] + (size_t)ks * 294912];  // 1024*288
#pragma unroll
    for (int mf = 0; mf < 4; ++mf) {
      int o = obase + mf * 16 + ln;
      bf16x8 ah = *(const bf16x8*)&w_hi[o * 256 + ks * 32 + qq * 8];
      bf16x8 al = *(const bf16x8*)&w_lo[o * 256 + ks * 32 + qq * 8];
#pragma unroll
      for (int nf = 0; nf < 4; ++nf) {
        acc[mf][nf] = __builtin_amdgcn_mfma_f32_16x16x32_bf16(ah, bfr[nf], acc[mf][nf], 0, 0, 0);
        acc[mf][nf] = __builtin_amdgcn_mfma_f32_16x16x32_bf16(al, bfr[nf], acc[mf][nf], 0, 0, 0);
      }
    }
  }
#pragma unroll
  for (int mf = 0; mf < 4; ++mf) {
#pragma unroll
    for (int r = 0; r < 4; ++r) {
      int o = obase + mf * 16 + qq * 4 + r;
      float bias = b_out[o];
#pragma unroll
      for (int nf = 0; nf < 4; ++nf) {
        int p = p_base + nf * 16 + ln;
        out[((size_t)b * 256 + o) * 9216 + p] = acc[mf][nf][r] + bias;
      }
    }
  }
}

extern "C" void kernel_launch(void* const* d_in, const int* in_sizes, int n_in,
                              void* d_out, int out_size, void* d_ws, size_t ws_size,
                              hipStream_t stream) {
  const float* x     = (const float*)d_in[0];
  const float* w_qkv = (const float*)d_in[1];
  const float* gtok  = (const float*)d_in[2];
  const float* ln_g  = (const float*)d_in[3];
  const float* ln_b  = (const float*)d_in[4];
  const float* w_qk  = (const float*)d_in[5];
  const float* b_qk  = (const float*)d_in[6];
  const float* w_out = (const float*)d_in[7];
  const float* b_out = (const float*)d_in[8];
  float* out = (float*)d_out;

  // layout (shorts):
  unsigned short* ws   = (unsigned short*)d_ws;
  unsigned short* w_bf = ws;                        // 196,608
  unsigned short* w_hi = ws + 196608;               // 65,536
  unsigned short* w_lo = ws + 262144;               // 65,536
  unsigned short* tok  = ws + 327680;               // 768 (+pad)
  unsigned short* t_b  = ws + 328704;               // 4,194,304
  unsigned short* wq_b = ws + 4523008;              // 4,194,304
  unsigned short* wk_b = ws + 8717312;              // 4,194,304
  unsigned short* gf_t = ws + 12911616;             // 37,748,736
  unsigned short* R    = ws + 50660352;             // qkv+xt chunks, later agg

  auto need = [](int NBv) -> size_t {
    size_t reg = (size_t)NBv * 9437184ull;          // qkv + xt per chunk
    if (reg < 37748736ull) reg = 37748736ull;       // agg alias floor
    return (50660352ull + reg) * 2ull;
  };
  int NB = 4;
  if (ws_size >= need(16)) NB = 16;
  else if (ws_size >= need(8)) NB = 8;

  unsigned short* qkv = R;
  unsigned short* xt  = R + (size_t)NB * 7077888ull;
  unsigned short* agg_b = R;
  // w_qk hi/lo live in the (dead-after-chunks) xt region; k_qk reads them
  // before k_flash overwrites R with agg (stream-ordered).
  unsigned short* wqk_hi = xt;
  unsigned short* wqk_lo = xt + 131072;

  k_wcvt<<<1024, 256, 0, stream>>>(w_qkv, w_out, w_bf, w_hi, w_lo);
  k_tok<<<3, 256, 0, stream>>>(w_qkv, gtok, tok);
  for (int c = 0; c < 16 / NB; ++c) {
    int b0 = c * NB;
    k_xt<<<NB * 576, 256, 0, stream>>>(x, xt, b0);
    k_qkv<<<NB * 432, 256, 0, stream>>>(w_bf, xt, qkv);
    k_attn<<<NB * 512, 256, 0, stream>>>(qkv, tok, ln_g, ln_b, t_b, gf_t, b0);
  }
  k_wqkcvt<<<512, 256, 0, stream>>>(w_qk, wqk_hi, wqk_lo);
  k_qk<<<512, 256, 0, stream>>>(t_b, wqk_hi, wqk_lo, b_qk, wq_b, wk_b);
  k_flash<<<2048, 256, 0, stream>>>(wq_b, wk_b, gf_t, agg_b);
  k_out<<<2304, 256, 0, stream>>>(agg_b, w_hi, w_lo, b_out, out);
}